// Round 14
// baseline (214.653 us; speedup 1.0000x reference)
//
#include <hip/hip_runtime.h>

// ---------------- problem constants ----------------
constexpr int KC    = 4096;      // NUM_EMBEDDINGS
constexpr int DIM   = 64;        // EMBEDDING_DIM
constexpr int NROWS = 73728;     // 128*24*1536/64
constexpr int NELEM = 4718592;   // 128*24*1536
constexpr int GB    = 8192;      // bytes per packed 32-code group (8 x 1KB frags)

typedef _Float16 f16x8  __attribute__((ext_vector_type(8)));
typedef float    f32x16 __attribute__((ext_vector_type(16)));

// ---------------- output layout (floats) ----------------
constexpr size_t OUT_LOSS  = 0;                               // 1
constexpr size_t OUT_ZQ    = 1;                               // NELEM
constexpr size_t OUT_CODES = 1 + (size_t)NELEM;               // NROWS
constexpr size_t OUT_EMB   = OUT_CODES + (size_t)NROWS;       // KC*DIM
constexpr size_t OUT_NCS   = OUT_EMB + (size_t)KC * DIM;      // KC
constexpr size_t OUT_NEW   = OUT_NCS + (size_t)KC;            // KC*DIM

// ---------------- workspace layout (bytes) ----------------
constexpr size_t alignup(size_t x, size_t a) { return (x + a - 1) & ~(a - 1); }
constexpr size_t WS_CODES  = 0;                                            // int[NROWS]
constexpr size_t WS_COUNTS = WS_CODES + sizeof(int) * (size_t)NROWS;       // int[KC]
constexpr size_t WS_OFFS   = WS_COUNTS + sizeof(int) * (size_t)KC;         // int[KC+1]
constexpr size_t WS_CURSOR = alignup(WS_OFFS + sizeof(int) * (KC + 1), 16);// int[KC]
constexpr size_t WS_SORTED = WS_CURSOR + sizeof(int) * (size_t)KC;         // int[NROWS]
constexpr size_t WS_E2     = alignup(WS_SORTED + sizeof(int) * (size_t)NROWS, 64); // float[KC]
constexpr size_t WS_N      = WS_E2 + sizeof(float) * (size_t)KC;           // float[1]
constexpr size_t WS_LOSSD  = alignup(WS_N + sizeof(float), 8);             // double[1]
constexpr size_t WS_EMBPK  = alignup(WS_LOSSD + 8, 64);                    // 128*8192 = 1MB

// ---------------- kernel: pack emb -> 8KB 32-code group blocks + e2s + zero counts ----
// group g2 at g2*8192: frag cc (0..3) = e_hi k-chunk cc at cc*1024; frag 4+cc = 2^11*e_lo
// at 4096+cc*1024. lane = (q&1)*32 + (c&31) holds e[c][cc*16 + (q&1)*8 .. +8] (8 halves).
// e2s[c] = 2^11 * 0.5 * ||e_c||^2.
__global__ void k_prep(const float* __restrict__ emb, char* __restrict__ emb_pk,
                       float* __restrict__ e2s, int* __restrict__ counts) {
    if (threadIdx.x < 32) counts[blockIdx.x * 32 + threadIdx.x] = 0;
    int t = blockIdx.x * 256 + threadIdx.x;   // 0 .. 32767
    int c = t >> 3, q = t & 7;                // code, 8-dim chunk
    const float* ep = emb + (size_t)c * DIM + q * 8;
    f16x8 hv, lv;
    float s = 0.f;
    #pragma unroll
    for (int e = 0; e < 8; ++e) {
        float x = ep[e];
        _Float16 h = (_Float16)x;
        float r = x - (float)h;
        hv[e] = h;                          // raw e_hi
        lv[e] = (_Float16)(r * 2048.0f);    // 2^11 * e_lo
        s = fmaf(x, x, s);
    }
    s += __shfl_xor(s, 1, 64);
    s += __shfl_xor(s, 2, 64);
    s += __shfl_xor(s, 4, 64);
    if (q == 0) e2s[c] = 1024.0f * s;       // 2^11 * (0.5 * sum e^2)
    int g2 = c >> 5, col = c & 31;
    int cc = q >> 1, h2 = q & 1;
    int lane = h2 * 32 + col;
    char* base = emb_pk + (size_t)g2 * GB + cc * 1024 + lane * 16;
    *(f16x8*)base            = hv;
    *(f16x8*)(base + 4096)   = lv;
}

// ---------------- kernel: 32x32x16 MFMA distance argmin, vmcnt register pipeline ------
// 1152 blocks x 128 threads (2 independent waves, 32 rows each). Wave sweeps all 128
// 32-code groups; ONE 12-MFMA chain per group into a 16-reg acc (2x FLOP/instr vs
// 16x16). 2-stage asm-pinned load pipeline (9 loads/group), vmcnt(9) per group.
// Tail: wrap offsets ONLY for the final dummy issue (group 128) — group 127 is real.
// dist' = 2^11*(0.5||e||^2 - z.e): C-init=2^11 e2h; (-2^11 z_hi).e_hi x4;
// (-z_hi).(2^11 e_lo) x4; (-2^11 z_lo).e_hi x4.
__global__ __launch_bounds__(128, 2) void k_argmin13(
        const float* __restrict__ z, const char* __restrict__ emb_pk,
        const float* __restrict__ e2s,
        int* __restrict__ codes_i, float* __restrict__ codes_f,
        int* __restrict__ counts) {
    __shared__ int codebuf[2][32];

    const int tid = threadIdx.x;
    const int l   = tid & 63;
    const int w   = tid >> 6;
    const int col = l & 31;      // code-in-group / A-row class
    const int h2  = l >> 5;      // k-half
    const int waveRow = blockIdx.x * 64 + w * 32;

    // ---- A fragments: 32 z-rows -> three negated scaled forms x 4 k-chunks ----
    f16x8 ah2k[4], ahr[4], al2k[4];
    #pragma unroll
    for (int c = 0; c < 4; ++c) {
        const float* zp = z + (size_t)(waveRow + col) * DIM + c * 16 + h2 * 8;
        float4 x0 = *(const float4*)zp;
        float4 x1 = *(const float4*)(zp + 4);
        float xs[8] = {x0.x, x0.y, x0.z, x0.w, x1.x, x1.y, x1.z, x1.w};
        #pragma unroll
        for (int e = 0; e < 8; ++e) {
            _Float16 hh = (_Float16)xs[e];
            float rr = xs[e] - (float)hh;
            ahr[c][e]  = -hh;
            ah2k[c][e] = (_Float16)(-2048.0f * (float)hh);   // exact pow2 scale
            al2k[c][e] = -(_Float16)(rr * 2048.0f);
        }
    }

    float best[16];
    int   bestg[16];
    #pragma unroll
    for (int r = 0; r < 16; ++r) { best[r] = INFINITY; bestg[r] = 0; }

    const unsigned long long pkb = (unsigned long long)emb_pk;
    const unsigned long long e2b = (unsigned long long)e2s;
    unsigned voffA = l * 16;            // frags 0-3 stream
    unsigned voffA2 = 4096 + l * 16;    // frags 4-7 stream
    unsigned voffB = col * 4;           // e2s stream

    f16x8 a0, a1, a2, a3, a4, a5, a6, a7;   // stage A: hi0-3, lo0-3
    f16x8 c0, c1, c2, c3, c4, c5, c6, c7;   // stage B
    float eA, eB;

#define ISSUE(B0, B1, B2, B3, B4, B5, B6, B7, EV)                                          \
    asm volatile("global_load_dword %0, %1, %2"               : "=v"(EV) : "v"(voffB), "s"(e2b)); \
    asm volatile("global_load_dwordx4 %0, %1, %2"             : "=v"(B0) : "v"(voffA), "s"(pkb)); \
    asm volatile("global_load_dwordx4 %0, %1, %2 offset:1024" : "=v"(B1) : "v"(voffA), "s"(pkb)); \
    asm volatile("global_load_dwordx4 %0, %1, %2 offset:2048" : "=v"(B2) : "v"(voffA), "s"(pkb)); \
    asm volatile("global_load_dwordx4 %0, %1, %2 offset:3072" : "=v"(B3) : "v"(voffA), "s"(pkb)); \
    asm volatile("global_load_dwordx4 %0, %1, %2"             : "=v"(B4) : "v"(voffA2), "s"(pkb)); \
    asm volatile("global_load_dwordx4 %0, %1, %2 offset:1024" : "=v"(B5) : "v"(voffA2), "s"(pkb)); \
    asm volatile("global_load_dwordx4 %0, %1, %2 offset:2048" : "=v"(B6) : "v"(voffA2), "s"(pkb)); \
    asm volatile("global_load_dwordx4 %0, %1, %2 offset:3072" : "=v"(B7) : "v"(voffA2), "s"(pkb)); \
    voffA += GB; voffA2 += GB; voffB += 128;

#define WRAP0 { voffA = l * 16; voffA2 = 4096 + l * 16; voffB = col * 4; }

#define WAITP                                                \
    asm volatile("s_waitcnt vmcnt(9)" ::: "memory");         \
    __builtin_amdgcn_sched_barrier(0);

#define COMP(B0, B1, B2, B3, B4, B5, B6, B7, EV, G) {                                      \
        f32x16 acc;                                                                        \
        _Pragma("unroll")                                                                  \
        for (int r = 0; r < 16; ++r) acc[r] = EV;                                          \
        acc = __builtin_amdgcn_mfma_f32_32x32x16_f16(ah2k[0], B0, acc, 0, 0, 0);           \
        acc = __builtin_amdgcn_mfma_f32_32x32x16_f16(ah2k[1], B1, acc, 0, 0, 0);           \
        acc = __builtin_amdgcn_mfma_f32_32x32x16_f16(ah2k[2], B2, acc, 0, 0, 0);           \
        acc = __builtin_amdgcn_mfma_f32_32x32x16_f16(ah2k[3], B3, acc, 0, 0, 0);           \
        acc = __builtin_amdgcn_mfma_f32_32x32x16_f16(ahr[0],  B4, acc, 0, 0, 0);           \
        acc = __builtin_amdgcn_mfma_f32_32x32x16_f16(ahr[1],  B5, acc, 0, 0, 0);           \
        acc = __builtin_amdgcn_mfma_f32_32x32x16_f16(ahr[2],  B6, acc, 0, 0, 0);           \
        acc = __builtin_amdgcn_mfma_f32_32x32x16_f16(ahr[3],  B7, acc, 0, 0, 0);           \
        acc = __builtin_amdgcn_mfma_f32_32x32x16_f16(al2k[0], B0, acc, 0, 0, 0);           \
        acc = __builtin_amdgcn_mfma_f32_32x32x16_f16(al2k[1], B1, acc, 0, 0, 0);           \
        acc = __builtin_amdgcn_mfma_f32_32x32x16_f16(al2k[2], B2, acc, 0, 0, 0);           \
        acc = __builtin_amdgcn_mfma_f32_32x32x16_f16(al2k[3], B3, acc, 0, 0, 0);           \
        _Pragma("unroll")                                                                  \
        for (int r = 0; r < 16; ++r)                                                       \
            if (acc[r] < best[r]) { best[r] = acc[r]; bestg[r] = (G); }                    \
    }

    __builtin_amdgcn_sched_barrier(0);   // keep A-prep above the asm stream
    ISSUE(a0, a1, a2, a3, a4, a5, a6, a7, eA)        // group 0

    #pragma unroll 1
    for (int g = 0; g < 128; g += 2) {
        ISSUE(c0, c1, c2, c3, c4, c5, c6, c7, eB)     // group g+1 (always real: <=127)
        WAITP
        COMP(a0, a1, a2, a3, a4, a5, a6, a7, eA, g)
        if (g == 126) WRAP0                           // ONLY the final dummy issue wraps
        ISSUE(a0, a1, a2, a3, a4, a5, a6, a7, eA)     // group g+2, or wrapped dummy
        WAITP
        COMP(c0, c1, c2, c3, c4, c5, c6, c7, eB, g + 1)
    }
    asm volatile("s_waitcnt vmcnt(0)" ::: "memory");   // drain wrapped tail loads
    __builtin_amdgcn_sched_barrier(0);
#undef ISSUE
#undef WRAP0
#undef WAITP
#undef COMP

    // ---- butterfly argmin over the 32 code-classes within each lane half ----
    #pragma unroll
    for (int r = 0; r < 16; ++r) {
        float b = best[r];
        int   k = bestg[r] * 32 + col;
        #pragma unroll
        for (int m = 1; m < 32; m <<= 1) {
            float obv = __shfl_xor(b, m, 64);
            int   okv = __shfl_xor(k, m, 64);
            if (obv < b || (obv == b && okv < k)) { b = obv; k = okv; }
        }
        if (col == 0) codebuf[w][(r & 3) + 8 * (r >> 2) + 4 * h2] = k;  // D row map
    }

    // ---- emit codes + int counts (within-wave LDS dep only; no barrier) ----
    if (l < 32) {
        int code = codebuf[w][l];
        size_t rowg = (size_t)waveRow + l;
        codes_i[rowg] = code;
        codes_f[rowg] = (float)code;
        atomicAdd(&counts[code], 1);
    }
}

// ---------------- kernel: scan counts -> offsets/cursor + cluster-size + n + loss=0 ----
__global__ void k_scan(const int* __restrict__ counts,
                       int* __restrict__ offsets, int* __restrict__ cursor,
                       const float* __restrict__ ema_cs, float* __restrict__ ncs_out,
                       float* __restrict__ n_out, double* __restrict__ lossp) {
    __shared__ int   part[256];
    __shared__ float fpart[256];
    int tid = threadIdx.x;
    if (tid == 0) *lossp = 0.0;
    int base = tid * 16;
    int loc[16];
    int s = 0;
    float fs = 0.f;
    #pragma unroll
    for (int j = 0; j < 16; ++j) {
        int cnt = counts[base + j];
        loc[j] = s; s += cnt;
        float v = 0.99f * ema_cs[base + j] + 0.01f * (float)cnt;
        ncs_out[base + j] = v;
        fs += v;
    }
    part[tid] = s;
    fpart[tid] = fs;
    __syncthreads();
    for (int off = 1; off < 256; off <<= 1) {
        int v = (tid >= off) ? part[tid - off] : 0;
        __syncthreads();
        part[tid] += v;
        __syncthreads();
    }
    int excl = part[tid] - s;
    #pragma unroll
    for (int j = 0; j < 16; ++j) {
        int o = excl + loc[j];
        offsets[base + j] = o;
        cursor[base + j]  = o;
    }
    if (tid == 255) offsets[KC] = excl + s;
    for (int m = 128; m > 0; m >>= 1) {
        if (tid < m) fpart[tid] += fpart[tid + m];
        __syncthreads();
    }
    if (tid == 0) n_out[0] = fpart[0];
}

// ---------------- kernel: scatter row indices into code-sorted order ----------------
__global__ void k_scatteridx(const int* __restrict__ codes_i,
                             int* __restrict__ cursor, int* __restrict__ sorted_rows) {
    int r = blockIdx.x * 256 + threadIdx.x;
    if (r < NROWS) {
        int c = codes_i[r];
        int p = atomicAdd(&cursor[c], 1);
        sorted_rows[p] = r;
    }
}

// ---------------- kernel: segmented sum -> dw, fused EMA-w + new embedding ----------------
__global__ __launch_bounds__(64) void k_dwsum(
        const float* __restrict__ z, const int* __restrict__ offsets,
        const int* __restrict__ sorted_rows, const float* __restrict__ ema_w,
        const float* __restrict__ ncs, const float* __restrict__ nptr,
        float* __restrict__ new_ema_w_out, float* __restrict__ new_emb_out) {
    int k = blockIdx.x, tid = threadIdx.x;
    int beg = offsets[k], end = offsets[k + 1];
    float a0 = 0.f, a1 = 0.f, a2 = 0.f, a3 = 0.f;
    int i = beg;
    for (; i + 3 < end; i += 4) {
        int r0 = sorted_rows[i], r1 = sorted_rows[i + 1];
        int r2 = sorted_rows[i + 2], r3 = sorted_rows[i + 3];
        a0 += z[(size_t)r0 * DIM + tid];
        a1 += z[(size_t)r1 * DIM + tid];
        a2 += z[(size_t)r2 * DIM + tid];
        a3 += z[(size_t)r3 * DIM + tid];
    }
    for (; i < end; ++i) a0 += z[(size_t)sorted_rows[i] * DIM + tid];
    float dwv = (a0 + a1) + (a2 + a3);
    size_t idx = (size_t)k * DIM + tid;
    float n = nptr[0];
    float nw = 0.99f * ema_w[idx] + 0.01f * dwv;
    float cs = (ncs[k] + 1e-5f) / (n + 4096.0f * 1e-5f) * n;
    new_ema_w_out[idx] = nw;
    new_emb_out[idx] = nw / cs;
}

// ---------------- kernel: quantize + straight-through + loss ----------------
__global__ __launch_bounds__(256) void k_quant(
        const float* __restrict__ z, const float* __restrict__ new_emb,
        const int* __restrict__ codes, float* __restrict__ zq_out,
        double* __restrict__ loss_acc) {
    __shared__ double red[256];
    const int nvec = NELEM / 4;
    int t = blockIdx.x * 256 + threadIdx.x;
    int stride = gridDim.x * 256;
    double ls = 0.0;
    for (int v = t; v < nvec; v += stride) {
        int e0 = v * 4;
        int n  = e0 >> 6;
        int d0 = e0 & 63;
        int code = codes[n];
        float4 zq = *(const float4*)&new_emb[(size_t)code * DIM + d0];
        float4 zv = *(const float4*)&z[e0];
        float dx = zq.x - zv.x, dy = zq.y - zv.y, dz = zq.z - zv.z, dw4 = zq.w - zv.w;
        float4 o;
        o.x = zv.x + dx; o.y = zv.y + dy; o.z = zv.z + dz; o.w = zv.w + dw4;
        *(float4*)&zq_out[e0] = o;
        ls += (double)(dx * dx) + (double)(dy * dy) + (double)(dz * dz) + (double)(dw4 * dw4);
    }
    red[threadIdx.x] = ls;
    __syncthreads();
    for (int m = 128; m > 0; m >>= 1) {
        if (threadIdx.x < m) red[threadIdx.x] += red[threadIdx.x + m];
        __syncthreads();
    }
    if (threadIdx.x == 0) atomicAdd(loss_acc, red[0]);
}

__global__ void k_loss(const double* __restrict__ loss_acc, float* __restrict__ out0) {
    out0[0] = (float)(0.25 * (loss_acc[0] / (double)NELEM));
}

// ---------------- launcher ----------------
extern "C" void kernel_launch(void* const* d_in, const int* in_sizes, int n_in,
                              void* d_out, int out_size, void* d_ws, size_t ws_size,
                              hipStream_t stream) {
    const float* z      = (const float*)d_in[0];
    const float* emb    = (const float*)d_in[1];
    const float* ema_cs = (const float*)d_in[2];
    const float* ema_w  = (const float*)d_in[3];
    float* out = (float*)d_out;
    char*  ws  = (char*)d_ws;

    int*    codes_i = (int*)(ws + WS_CODES);
    int*    counts  = (int*)(ws + WS_COUNTS);
    int*    offsets = (int*)(ws + WS_OFFS);
    int*    cursor  = (int*)(ws + WS_CURSOR);
    int*    sorted  = (int*)(ws + WS_SORTED);
    float*  e2s     = (float*)(ws + WS_E2);
    float*  nptr    = (float*)(ws + WS_N);
    double* lossp   = (double*)(ws + WS_LOSSD);
    char*   emb_pk  = ws + WS_EMBPK;

    k_prep<<<(KC * 8) / 256, 256, 0, stream>>>(emb, emb_pk, e2s, counts);
    k_argmin13<<<NROWS / 64, 128, 0, stream>>>(z, emb_pk, e2s, codes_i,
                                               out + OUT_CODES, counts);
    k_scan<<<1, 256, 0, stream>>>(counts, offsets, cursor, ema_cs,
                                  out + OUT_NCS, nptr, lossp);
    k_scatteridx<<<(NROWS + 255) / 256, 256, 0, stream>>>(codes_i, cursor, sorted);
    k_dwsum<<<KC, 64, 0, stream>>>(z, offsets, sorted, ema_w,
                                   out + OUT_NCS, nptr, out + OUT_NEW, out + OUT_EMB);
    k_quant<<<1152, 256, 0, stream>>>(z, out + OUT_EMB, codes_i,
                                      out + OUT_ZQ, lossp);
    k_loss<<<1, 1, 0, stream>>>(lossp, out + OUT_LOSS);
}